// Round 1
// baseline (211.739 us; speedup 1.0000x reference)
//
#include <hip/hip_runtime.h>

typedef __attribute__((ext_vector_type(8))) short bf16x8;
typedef __attribute__((ext_vector_type(4))) float f32x4;

// ---------------------------------------------------------------------------
// Posit(8,1) round-to-nearest quantization, bit-exact vs the jnp reference.
// two_es=2, npat=6, maxpos=2^12, minpos=2^-12. Result has <=4 fraction bits ->
// exactly representable in bf16 (and fp32).
// ---------------------------------------------------------------------------
__device__ __forceinline__ float posit_q(float x) {
  float ax = fabsf(x);
  ax = fmaxf(ax, 0x1p-12f);
  ax = fminf(ax, 0x1p12f);
  int s = (int)(__float_as_uint(ax) >> 23) - 127;   // floor(log2(ax)), exact
  int k = s >> 1;                                   // floor(s/2)
  int rlen = (k >= 0) ? (k + 2) : (1 - k);
  int fbits = 6 - rlen;
  fbits = fbits < 0 ? 0 : fbits;
  float m = ax * __uint_as_float((unsigned)(127 - s) << 23);  // [1,2)
  float fs = (float)(1 << fbits);
  float inv_fs = __uint_as_float((unsigned)(127 - fbits) << 23);
  float mq = rintf(m * fs) * inv_fs;                // round-half-even = jnp.round
  if (mq >= 2.0f) { s += 1; mq = 1.0f; }            // mantissa carry
  float y = mq * __uint_as_float((unsigned)(127 + s) << 23);
  y = fminf(y, 0x1p12f);
  y = copysignf(y, x);
  return (x == 0.0f) ? 0.0f : y;
}

// float4-vectorized quantize -> bf16 (truncate: value is exact in bf16)
__global__ void posit_quant_bf16(const float* __restrict__ in,
                                 ushort* __restrict__ out, int n4) {
  int i = blockIdx.x * blockDim.x + threadIdx.x;
  int stride = gridDim.x * blockDim.x;
  for (; i < n4; i += stride) {
    float4 v = ((const float4*)in)[i];
    ushort4 o;
    o.x = (ushort)(__float_as_uint(posit_q(v.x)) >> 16);
    o.y = (ushort)(__float_as_uint(posit_q(v.y)) >> 16);
    o.z = (ushort)(__float_as_uint(posit_q(v.z)) >> 16);
    o.w = (ushort)(__float_as_uint(posit_q(v.w)) >> 16);
    ((ushort4*)out)[i] = o;
  }
}

__global__ void posit_quant_f32(const float* __restrict__ in,
                                float* __restrict__ out, int n) {
  int i = blockIdx.x * blockDim.x + threadIdx.x;
  if (i < n) out[i] = posit_q(in[i]);
}

// ---------------------------------------------------------------------------
// bf16 NT GEMM (A: MxK row-major, B: NxK row-major), C = A*B^T + bias.
// m97 structure: 128x128 tile, BK=32, 4 waves (2x2), 4x4 16x16x32 MFMA/wave,
// global_load_lds width=16 staging, 2-barrier K-loop.
// ---------------------------------------------------------------------------
__device__ __forceinline__ void gl_lds16(const ushort* g, ushort* l) {
  __builtin_amdgcn_global_load_lds(
      (const __attribute__((address_space(1))) void*)g,
      (__attribute__((address_space(3))) void*)l,
      16, 0, 0);
}

__global__ __launch_bounds__(256, 2) void posit_gemm(
    const ushort* __restrict__ A, const ushort* __restrict__ B,
    const float* __restrict__ bq, float* __restrict__ C,
    int M, int N, int K) {
  __shared__ ushort sA[128 * 32];   // 8 KB, row-major [128][32]
  __shared__ ushort sB[128 * 32];   // 8 KB

  const int tid = threadIdx.x;
  const int wave = tid >> 6;
  const int lane = tid & 63;
  const int wm = wave >> 1;         // 2x2 wave grid, 64x64 per wave
  const int wn = wave & 1;
  const int m0 = blockIdx.y << 7;
  const int n0 = blockIdx.x << 7;

  // staging: chunk c = 8 bf16 = 16 B; lds dest = wave-uniform base + lane*16
  const int c0 = (wave << 6) + lane;       // chunks 0..255 (round 0)
  const int r0 = c0 >> 2;                  // tile row 0..63
  const int q0 = (c0 & 3) << 3;            // k-offset 0/8/16/24
  const int r1 = r0 + 64;                  // round 1: rows 64..127

  const ushort* Ag0 = A + (size_t)(m0 + r0) * K + q0;
  const ushort* Ag1 = A + (size_t)(m0 + r1) * K + q0;
  const ushort* Bg0 = B + (size_t)(n0 + r0) * K + q0;
  const ushort* Bg1 = B + (size_t)(n0 + r1) * K + q0;

  ushort* lA0 = sA + (wave << 9);          // wave*512 elements (1 KB)
  ushort* lA1 = sA + 2048 + (wave << 9);
  ushort* lB0 = sB + (wave << 9);
  ushort* lB1 = sB + 2048 + (wave << 9);

  const int fr = lane & 15;                // fragment row (m or n)
  const int fk = (lane >> 4) << 3;         // fragment k-offset 0/8/16/24

  f32x4 acc[4][4];
#pragma unroll
  for (int i = 0; i < 4; i++)
#pragma unroll
    for (int j = 0; j < 4; j++) acc[i][j] = (f32x4){0.f, 0.f, 0.f, 0.f};

  for (int k0 = 0; k0 < K; k0 += 32) {
    gl_lds16(Ag0 + k0, lA0);
    gl_lds16(Ag1 + k0, lA1);
    gl_lds16(Bg0 + k0, lB0);
    gl_lds16(Bg1 + k0, lB1);
    __syncthreads();                        // drains vmcnt before barrier

    bf16x8 fa[4], fb[4];
#pragma unroll
    for (int i = 0; i < 4; i++)
      fa[i] = *(const bf16x8*)(sA + (((wm << 6) + (i << 4) + fr) << 5) + fk);
#pragma unroll
    for (int j = 0; j < 4; j++)
      fb[j] = *(const bf16x8*)(sB + (((wn << 6) + (j << 4) + fr) << 5) + fk);

#pragma unroll
    for (int i = 0; i < 4; i++)
#pragma unroll
      for (int j = 0; j < 4; j++)
        acc[i][j] = __builtin_amdgcn_mfma_f32_16x16x32_bf16(
            fa[i], fb[j], acc[i][j], 0, 0, 0);
    __syncthreads();
  }

  // Epilogue: C/D layout col = lane&15, row = (lane>>4)*4 + reg. Fuse bias.
  const int row0 = m0 + (wm << 6) + ((lane >> 4) << 2);
  const int col0 = n0 + (wn << 6) + fr;
#pragma unroll
  for (int j = 0; j < 4; j++) {
    const int col = col0 + (j << 4);
    const float bv = bq[col];
#pragma unroll
    for (int i = 0; i < 4; i++) {
      const int row = row0 + (i << 4);
#pragma unroll
      for (int r = 0; r < 4; r++)
        C[(size_t)(row + r) * N + col] = acc[i][j][r] + bv;
    }
  }
}

extern "C" void kernel_launch(void* const* d_in, const int* in_sizes, int n_in,
                              void* d_out, int out_size, void* d_ws, size_t ws_size,
                              hipStream_t stream) {
  const float* x = (const float*)d_in[0];
  const float* w = (const float*)d_in[1];
  const float* bias = (const float*)d_in[2];
  float* out = (float*)d_out;

  const int out_f = in_sizes[2];                 // 2048
  const int in_f = in_sizes[1] / out_f;          // 2048
  const int m = in_sizes[0] / in_f;              // 8192
  const int k = in_f;

  // workspace layout: Xq bf16 | Wq bf16 | bq fp32
  ushort* Xq = (ushort*)d_ws;
  ushort* Wq = Xq + (size_t)m * k;
  float* bquant = (float*)(Wq + (size_t)out_f * k);

  {
    int n4 = in_sizes[0] / 4;
    int blocks = (n4 + 255) / 256;
    if (blocks > 16384) blocks = 16384;
    posit_quant_bf16<<<blocks, 256, 0, stream>>>(x, Xq, n4);
  }
  {
    int n4 = in_sizes[1] / 4;
    int blocks = (n4 + 255) / 256;
    if (blocks > 16384) blocks = 16384;
    posit_quant_bf16<<<blocks, 256, 0, stream>>>(w, Wq, n4);
  }
  posit_quant_f32<<<(out_f + 255) / 256, 256, 0, stream>>>(bias, bquant, out_f);

  dim3 grid(out_f / 128, m / 128);
  posit_gemm<<<grid, 256, 0, stream>>>(Xq, Wq, bquant, out, m, out_f, k);
}

// Round 2
// 205.862 us; speedup vs baseline: 1.0285x; 1.0285x over previous
//
#include <hip/hip_runtime.h>

typedef __attribute__((ext_vector_type(8))) short bf16x8;
typedef __attribute__((ext_vector_type(4))) float f32x4;

// ---------------------------------------------------------------------------
// Posit(8,1) round-to-nearest quantization, bit-exact vs the jnp reference.
// two_es=2, npat=6, maxpos=2^12, minpos=2^-12. Result has <=4 fraction bits ->
// exactly representable in bf16 (and fp32).
// ---------------------------------------------------------------------------
__device__ __forceinline__ float posit_q(float x) {
  float ax = fabsf(x);
  ax = fmaxf(ax, 0x1p-12f);
  ax = fminf(ax, 0x1p12f);
  int s = (int)(__float_as_uint(ax) >> 23) - 127;   // floor(log2(ax)), exact
  int k = s >> 1;                                   // floor(s/2)
  int rlen = (k >= 0) ? (k + 2) : (1 - k);
  int fbits = 6 - rlen;
  fbits = fbits < 0 ? 0 : fbits;
  float m = ax * __uint_as_float((unsigned)(127 - s) << 23);  // [1,2)
  float fs = (float)(1 << fbits);
  float inv_fs = __uint_as_float((unsigned)(127 - fbits) << 23);
  float mq = rintf(m * fs) * inv_fs;                // round-half-even = jnp.round
  if (mq >= 2.0f) { s += 1; mq = 1.0f; }            // mantissa carry
  float y = mq * __uint_as_float((unsigned)(127 + s) << 23);
  y = fminf(y, 0x1p12f);
  y = copysignf(y, x);
  return (x == 0.0f) ? 0.0f : y;
}

__device__ __forceinline__ ushort4 quant4_bf16(float4 v) {
  ushort4 o;
  o.x = (ushort)(__float_as_uint(posit_q(v.x)) >> 16);
  o.y = (ushort)(__float_as_uint(posit_q(v.y)) >> 16);
  o.z = (ushort)(__float_as_uint(posit_q(v.z)) >> 16);
  o.w = (ushort)(__float_as_uint(posit_q(v.w)) >> 16);
  return o;
}

// One merged quantize kernel: x -> bf16, w -> bf16, bias -> fp32.
__global__ void posit_quant_all(const float* __restrict__ x,
                                const float* __restrict__ w,
                                const float* __restrict__ b,
                                ushort* __restrict__ Xq,
                                ushort* __restrict__ Wq,
                                float* __restrict__ bq,
                                int nx4, int nw4, int nb4) {
  int i = blockIdx.x * blockDim.x + threadIdx.x;
  if (i < nx4) {
    ((ushort4*)Xq)[i] = quant4_bf16(((const float4*)x)[i]);
  } else if (i < nx4 + nw4) {
    int j = i - nx4;
    ((ushort4*)Wq)[j] = quant4_bf16(((const float4*)w)[j]);
  } else if (i < nx4 + nw4 + nb4) {
    int j = i - nx4 - nw4;
    float4 v = ((const float4*)b)[j];
    float4 o;
    o.x = posit_q(v.x); o.y = posit_q(v.y);
    o.z = posit_q(v.z); o.w = posit_q(v.w);
    ((float4*)bq)[j] = o;
  }
}

// ---------------------------------------------------------------------------
// bf16 NT GEMM (A: MxK row-major, B: NxK row-major), C = A*B^T + bias.
// m97 structure: 128x128 tile, BK=32, 4 waves (2x2), 4x4 16x16x32 MFMA/wave,
// global_load_lds width=16 staging, 2-barrier K-loop.
//
// Bank-conflict fix: LDS row stride is 64 B = 16 banks, so rows 2 apart alias
// the same banks -> 8-way conflict on fragment ds_read_b128 (R1 counters:
// 8.4M conflict cycles). XOR-swizzle the 16B k-chunk position within each row
// by s(row) = (row>>1)&3: each 16-lane quad then covers all 8 bank-groups
// exactly twice (2-way = free). Staging lanes load the correspondingly
// permuted chunk of the same 64B row segment (coalescing preserved); readers
// apply the same XOR. Row bases are multiples of 16, so s depends only on the
// low 4 row bits -> per-thread constant.
// ---------------------------------------------------------------------------
__device__ __forceinline__ void gl_lds16(const ushort* g, ushort* l) {
  __builtin_amdgcn_global_load_lds(
      (const __attribute__((address_space(1))) void*)g,
      (__attribute__((address_space(3))) void*)l,
      16, 0, 0);
}

__global__ __launch_bounds__(256, 2) void posit_gemm(
    const ushort* __restrict__ A, const ushort* __restrict__ B,
    const float* __restrict__ bq, float* __restrict__ C,
    int M, int N, int K) {
  __shared__ ushort sA[128 * 32];   // 8 KB, row-major [128][32], chunk-swizzled
  __shared__ ushort sB[128 * 32];   // 8 KB

  const int tid = threadIdx.x;
  const int wave = tid >> 6;
  const int lane = tid & 63;
  const int wm = wave >> 1;         // 2x2 wave grid, 64x64 per wave
  const int wn = wave & 1;
  const int m0 = blockIdx.y << 7;
  const int n0 = blockIdx.x << 7;

  // staging: chunk c = 8 bf16 = 16 B; lds dest = wave-uniform base + lane*16.
  // LDS granule (r0, p0) holds global chunk p0 ^ s(r0).
  const int c0 = (wave << 6) + lane;             // 0..255 (round 0)
  const int r0 = c0 >> 2;                        // tile row 0..63
  const int p0 = c0 & 3;                         // LDS chunk position
  const int q0 = ((p0 ^ ((r0 >> 1) & 3)) << 3);  // global k-elem offset (swizzled)
  const int r1 = r0 + 64;                        // round 1: rows 64..127, same s

  const ushort* Ag0 = A + (size_t)(m0 + r0) * K + q0;
  const ushort* Ag1 = A + (size_t)(m0 + r1) * K + q0;
  const ushort* Bg0 = B + (size_t)(n0 + r0) * K + q0;
  const ushort* Bg1 = B + (size_t)(n0 + r1) * K + q0;

  ushort* lA0 = sA + (wave << 9);          // wave*512 elements (1 KB)
  ushort* lA1 = sA + 2048 + (wave << 9);
  ushort* lB0 = sB + (wave << 9);
  ushort* lB1 = sB + 2048 + (wave << 9);

  const int fr = lane & 15;                      // fragment row (m or n)
  // swizzled k-chunk position for this lane's fragment reads
  const int fkp = (((lane >> 4) ^ ((fr >> 1) & 3)) << 3);

  f32x4 acc[4][4];
#pragma unroll
  for (int i = 0; i < 4; i++)
#pragma unroll
    for (int j = 0; j < 4; j++) acc[i][j] = (f32x4){0.f, 0.f, 0.f, 0.f};

  for (int k0 = 0; k0 < K; k0 += 32) {
    gl_lds16(Ag0 + k0, lA0);
    gl_lds16(Ag1 + k0, lA1);
    gl_lds16(Bg0 + k0, lB0);
    gl_lds16(Bg1 + k0, lB1);
    __syncthreads();                        // drains vmcnt before barrier

    bf16x8 fa[4], fb[4];
#pragma unroll
    for (int i = 0; i < 4; i++)
      fa[i] = *(const bf16x8*)(sA + (((wm << 6) + (i << 4) + fr) << 5) + fkp);
#pragma unroll
    for (int j = 0; j < 4; j++)
      fb[j] = *(const bf16x8*)(sB + (((wn << 6) + (j << 4) + fr) << 5) + fkp);

#pragma unroll
    for (int i = 0; i < 4; i++)
#pragma unroll
      for (int j = 0; j < 4; j++)
        acc[i][j] = __builtin_amdgcn_mfma_f32_16x16x32_bf16(
            fa[i], fb[j], acc[i][j], 0, 0, 0);
    __syncthreads();
  }

  // Epilogue: C/D layout col = lane&15, row = (lane>>4)*4 + reg. Fuse bias.
  const int row0 = m0 + (wm << 6) + ((lane >> 4) << 2);
  const int col0 = n0 + (wn << 6) + fr;
#pragma unroll
  for (int j = 0; j < 4; j++) {
    const int col = col0 + (j << 4);
    const float bv = bq[col];
#pragma unroll
    for (int i = 0; i < 4; i++) {
      const int row = row0 + (i << 4);
#pragma unroll
      for (int r = 0; r < 4; r++)
        C[(size_t)(row + r) * N + col] = acc[i][j][r] + bv;
    }
  }
}

extern "C" void kernel_launch(void* const* d_in, const int* in_sizes, int n_in,
                              void* d_out, int out_size, void* d_ws, size_t ws_size,
                              hipStream_t stream) {
  const float* x = (const float*)d_in[0];
  const float* w = (const float*)d_in[1];
  const float* bias = (const float*)d_in[2];
  float* out = (float*)d_out;

  const int out_f = in_sizes[2];                 // 2048
  const int in_f = in_sizes[1] / out_f;          // 2048
  const int m = in_sizes[0] / in_f;              // 8192
  const int k = in_f;

  // workspace layout: Xq bf16 | Wq bf16 | bq fp32
  ushort* Xq = (ushort*)d_ws;
  ushort* Wq = Xq + (size_t)m * k;
  float* bquant = (float*)(Wq + (size_t)out_f * k);

  const int nx4 = in_sizes[0] / 4;
  const int nw4 = in_sizes[1] / 4;
  const int nb4 = in_sizes[2] / 4;
  const int total4 = nx4 + nw4 + nb4;
  posit_quant_all<<<(total4 + 255) / 256, 256, 0, stream>>>(
      x, w, bias, Xq, Wq, bquant, nx4, nw4, nb4);

  dim3 grid(out_f / 128, m / 128);
  posit_gemm<<<grid, 256, 0, stream>>>(Xq, Wq, bquant, out, m, out_f, k);
}

// Round 3
// 188.719 us; speedup vs baseline: 1.1220x; 1.0908x over previous
//
#include <hip/hip_runtime.h>

typedef __attribute__((ext_vector_type(8))) short bf16x8;
typedef __attribute__((ext_vector_type(4))) float f32x4;

// ---------------------------------------------------------------------------
// Posit(8,1) round-to-nearest quantization, bit-exact vs the jnp reference.
// two_es=2, npat=6, maxpos=2^12, minpos=2^-12. Result has <=4 fraction bits ->
// exactly representable in bf16 (and fp32).
// ---------------------------------------------------------------------------
__device__ __forceinline__ float posit_q(float x) {
  float ax = fabsf(x);
  ax = fmaxf(ax, 0x1p-12f);
  ax = fminf(ax, 0x1p12f);
  int s = (int)(__float_as_uint(ax) >> 23) - 127;   // floor(log2(ax)), exact
  int k = s >> 1;                                   // floor(s/2)
  int rlen = (k >= 0) ? (k + 2) : (1 - k);
  int fbits = 6 - rlen;
  fbits = fbits < 0 ? 0 : fbits;
  float m = ax * __uint_as_float((unsigned)(127 - s) << 23);  // [1,2)
  float fs = (float)(1 << fbits);
  float inv_fs = __uint_as_float((unsigned)(127 - fbits) << 23);
  float mq = rintf(m * fs) * inv_fs;                // round-half-even = jnp.round
  if (mq >= 2.0f) { s += 1; mq = 1.0f; }            // mantissa carry
  float y = mq * __uint_as_float((unsigned)(127 + s) << 23);
  y = fminf(y, 0x1p12f);
  y = copysignf(y, x);
  return (x == 0.0f) ? 0.0f : y;
}

__device__ __forceinline__ ushort4 quant4_bf16(float4 v) {
  ushort4 o;
  o.x = (ushort)(__float_as_uint(posit_q(v.x)) >> 16);
  o.y = (ushort)(__float_as_uint(posit_q(v.y)) >> 16);
  o.z = (ushort)(__float_as_uint(posit_q(v.z)) >> 16);
  o.w = (ushort)(__float_as_uint(posit_q(v.w)) >> 16);
  return o;
}

// One merged quantize kernel: x -> bf16, w -> bf16, bias -> fp32.
__global__ void posit_quant_all(const float* __restrict__ x,
                                const float* __restrict__ w,
                                const float* __restrict__ b,
                                ushort* __restrict__ Xq,
                                ushort* __restrict__ Wq,
                                float* __restrict__ bq,
                                int nx4, int nw4, int nb4) {
  int i = blockIdx.x * blockDim.x + threadIdx.x;
  if (i < nx4) {
    ((ushort4*)Xq)[i] = quant4_bf16(((const float4*)x)[i]);
  } else if (i < nx4 + nw4) {
    int j = i - nx4;
    ((ushort4*)Wq)[j] = quant4_bf16(((const float4*)w)[j]);
  } else if (i < nx4 + nw4 + nb4) {
    int j = i - nx4 - nw4;
    float4 v = ((const float4*)b)[j];
    float4 o;
    o.x = posit_q(v.x); o.y = posit_q(v.y);
    o.z = posit_q(v.z); o.w = posit_q(v.w);
    ((float4*)bq)[j] = o;
  }
}

// ---------------------------------------------------------------------------
// bf16 NT GEMM (A: MxK row-major, B: NxK row-major), C = A*B^T + bias.
// 128x128 tile, BK=64 (R3: halves barrier/drain count vs BK=32; 32 MFMA per
// wave per barrier -- AITER-like amortization), 4 waves (2x2), 4x4
// 16x16x32 MFMA per k-step, global_load_lds width=16 staging.
//
// Swizzle (BK=64): LDS row stride = 128 B = all 32 banks, so the 16 B k-chunk
// at position p in row r is stored at position p ^ (r&7). Fragment reads then
// hit 8 distinct bank-groups within each 8-lane phase (R2 measured 0 conflicts
// with the analogous BK=32 swizzle). Staging: an 8-lane group reads one row's
// 128 B segment permuted within itself -> still coalesced; global_load_lds
// dests stay lane-contiguous.
// ---------------------------------------------------------------------------
__device__ __forceinline__ void gl_lds16(const ushort* g, ushort* l) {
  __builtin_amdgcn_global_load_lds(
      (const __attribute__((address_space(1))) void*)g,
      (__attribute__((address_space(3))) void*)l,
      16, 0, 0);
}

__global__ __launch_bounds__(256, 2) void posit_gemm(
    const ushort* __restrict__ A, const ushort* __restrict__ B,
    const float* __restrict__ bq, float* __restrict__ C,
    int M, int N, int K) {
  __shared__ ushort sA[128 * 64];   // 16 KB, row-major [128][64], chunk-swizzled
  __shared__ ushort sB[128 * 64];   // 16 KB

  const int tid = threadIdx.x;
  const int wave = tid >> 6;
  const int lane = tid & 63;
  const int wm = wave >> 1;         // 2x2 wave grid, 64x64 per wave
  const int wn = wave & 1;
  const int m0 = blockIdx.y << 7;
  const int n0 = blockIdx.x << 7;

  // --- staging (4 rounds x {A,B}): chunk c = ((r*4+wave)<<6)+lane, row=c>>3,
  // pos=c&7=lane&7, row&7 = lane>>3 (round-independent).
  const int g8 = lane >> 3;                       // 0..7
  const int qe = ((lane & 7) ^ g8) << 3;          // swizzled k-elem offset in [0,64)
  const int rb = (wave << 3) + g8;                // row base within 32-row round

  const ushort* Ag = A + (size_t)(m0 + rb) * K + qe;
  const ushort* Bg = B + (size_t)(n0 + rb) * K + qe;
  const size_t rstep = (size_t)32 * K;            // 32 rows per round

  // wave-uniform LDS bases per round (HW adds lane*16B)
  ushort* lA[4]; ushort* lB[4];
#pragma unroll
  for (int r = 0; r < 4; r++) {
    lA[r] = sA + (((r << 2) + wave) << 9);
    lB[r] = sB + (((r << 2) + wave) << 9);
  }

  // --- fragment read offsets: row = wm*64 + i*16 + fr; chunk pos for k-step
  // kk: p = kk*4 + (lane>>4); stored at p ^ (fr&7).
  const int fr = lane & 15;
  const int t4 = lane >> 4;                       // 0..3
  const int pk0 = ((t4 ^ (fr & 7)) << 3);         // k-step 0 elem offset
  const int pk1 = (((4 + t4) ^ (fr & 7)) << 3);   // k-step 1 elem offset

  f32x4 acc[4][4];
#pragma unroll
  for (int i = 0; i < 4; i++)
#pragma unroll
    for (int j = 0; j < 4; j++) acc[i][j] = (f32x4){0.f, 0.f, 0.f, 0.f};

  for (int k0 = 0; k0 < K; k0 += 64) {
#pragma unroll
    for (int r = 0; r < 4; r++) {
      gl_lds16(Ag + k0 + r * rstep, lA[r]);
      gl_lds16(Bg + k0 + r * rstep, lB[r]);
    }
    __syncthreads();                  // drains vmcnt before barrier

#pragma unroll
    for (int kk = 0; kk < 2; kk++) {
      const int pk = kk ? pk1 : pk0;
      bf16x8 fa[4], fb[4];
#pragma unroll
      for (int i = 0; i < 4; i++)
        fa[i] = *(const bf16x8*)(sA + (((wm << 6) + (i << 4) + fr) << 6) + pk);
#pragma unroll
      for (int j = 0; j < 4; j++)
        fb[j] = *(const bf16x8*)(sB + (((wn << 6) + (j << 4) + fr) << 6) + pk);

#pragma unroll
      for (int i = 0; i < 4; i++)
#pragma unroll
        for (int j = 0; j < 4; j++)
          acc[i][j] = __builtin_amdgcn_mfma_f32_16x16x32_bf16(
              fa[i], fb[j], acc[i][j], 0, 0, 0);
    }
    __syncthreads();
  }

  // Epilogue: C/D layout col = lane&15, row = (lane>>4)*4 + reg. Fuse bias.
  const int row0 = m0 + (wm << 6) + (t4 << 2);
  const int col0 = n0 + (wn << 6) + fr;
#pragma unroll
  for (int j = 0; j < 4; j++) {
    const int col = col0 + (j << 4);
    const float bv = bq[col];
#pragma unroll
    for (int i = 0; i < 4; i++) {
      const int row = row0 + (i << 4);
#pragma unroll
      for (int r = 0; r < 4; r++)
        C[(size_t)(row + r) * N + col] = acc[i][j][r] + bv;
    }
  }
}

extern "C" void kernel_launch(void* const* d_in, const int* in_sizes, int n_in,
                              void* d_out, int out_size, void* d_ws, size_t ws_size,
                              hipStream_t stream) {
  const float* x = (const float*)d_in[0];
  const float* w = (const float*)d_in[1];
  const float* bias = (const float*)d_in[2];
  float* out = (float*)d_out;

  const int out_f = in_sizes[2];                 // 2048
  const int in_f = in_sizes[1] / out_f;          // 2048
  const int m = in_sizes[0] / in_f;              // 8192
  const int k = in_f;

  // workspace layout: Xq bf16 | Wq bf16 | bq fp32
  ushort* Xq = (ushort*)d_ws;
  ushort* Wq = Xq + (size_t)m * k;
  float* bquant = (float*)(Wq + (size_t)out_f * k);

  const int nx4 = in_sizes[0] / 4;
  const int nw4 = in_sizes[1] / 4;
  const int nb4 = in_sizes[2] / 4;
  const int total4 = nx4 + nw4 + nb4;
  posit_quant_all<<<(total4 + 255) / 256, 256, 0, stream>>>(
      x, w, bias, Xq, Wq, bquant, nx4, nw4, nb4);

  dim3 grid(out_f / 128, m / 128);
  posit_gemm<<<grid, 256, 0, stream>>>(Xq, Wq, bquant, out, m, out_f, k);
}